// Round 6
// baseline (75.931 us; speedup 1.0000x reference)
//
#include <hip/hip_runtime.h>
#include <stdint.h>

// DTM layer: B=4, C=3, H=W=64. Unit-spaced lattice => dist^2 = di^2 + dj^2.
// Distance-sorted offset table is a compile-time constant (constexpr counting
// sort). Per pixel: walk offsets in increasing d2, accumulate weight until
// crossing bound = 0.05*sum(w), interpolate within the crossing element.
// Equal-d2 shells are order-invariant; the reference's max_k clip never binds.
//
// Round-6 = round-4 structure with two targeted fixes:
//  - VGPR <= 64 (__launch_bounds__(1024,8), unroll-8 live set) + 24.7 KB LDS
//    -> 2 blocks/CU (32 waves/CU) instead of round-4's 1 block/CU.
//  - Phase A is BRANCHLESS with a pure lgkm queue: entries arrive by one
//    coalesced global load per wave (vmcnt) and are broadcast per-entry with
//    v_readlane (VALU, no memory counter); the only lgkm ops are the weight
//    ds_reads, so unrolled batches drain cleanly (round-5's scalar-branch
//    skip broke this; round-4's s_loads polluted lgkmcnt).
//  - w has a 65th zero row: invalid-row gathers redirect there via a uniform
//    scalar cselect of the row base (no per-lane row cndmask).

#define HW     4096
#define NOFF   16129   // 127*127
#define NPAD   16384
#define NBIN   8192    // max d2 = 63^2+63^2 = 7938
#define NCHUNK 16      // speculative window = 1024 entries

struct Ent { uint32_t off; float d2; };   // off = (di+63)<<7 | (dj+63)
struct Tables { Ent e[NPAD]; };

constexpr Tables make_tables() {
    Tables t{};
    int cnt[NBIN] = {};
    for (int idx = 0; idx < NOFF; ++idx) {
        int di = idx / 127 - 63, dj = idx % 127 - 63;
        cnt[di * di + dj * dj]++;
    }
    int run = 0;
    for (int b = 0; b < NBIN; ++b) { int c = cnt[b]; cnt[b] = run; run += c; }
    for (int idx = 0; idx < NOFF; ++idx) {
        int di = idx / 127 - 63, dj = idx % 127 - 63;
        int d2 = di * di + dj * dj;
        int pos = cnt[d2]++;
        t.e[pos].off = (uint32_t)((di + 63) << 7) | (uint32_t)(dj + 63);
        t.e[pos].d2  = (float)d2;
    }
    for (int p = NOFF; p < NPAD; ++p) {
        t.e[p].off = 0u;     // di=-63, dj=-63: row invalid -> zero row; d2=0
        t.e[p].d2  = 0.0f;
    }
    return t;
}

__device__ const Tables g_t = make_tables();

__global__ __launch_bounds__(1024, 8) void dtm_kernel(const float* __restrict__ x,
                                                      float* __restrict__ out) {
    __shared__ float  w[HW + 64];            // 16.25 KB; row 64 = zeros
    __shared__ float2 summ[NCHUNK][64];      // 8 KB chunk partials
    __shared__ float  red[NCHUNK];

    int bc   = blockIdx.x >> 6;
    int pi   = blockIdx.x & 63;   // row (uniform)
    int tid  = threadIdx.x;
    int lane = tid & 63;          // pixel column
    int wv   = tid >> 6;          // wave id = chunk id

    // global loads first (both queues fill before any dependent use)
    const float4* xb = (const float4*)(x + (size_t)bc * HW);
    float4 v = xb[tid];
    const uint2* gt = (const uint2*)g_t.e;
    uint2 ev = gt[(wv << 6) | lane];   // entry `lane` of chunk `wv`

    ((float4*)w)[tid] = v;
    if (wv == 0) w[HW + lane] = 0.f;   // zero row
    float s = (v.x + v.y) + (v.z + v.w);
    #pragma unroll
    for (int off = 32; off >= 1; off >>= 1) s += __shfl_down(s, off, 64);
    if (lane == 0) red[wv] = s;
    __syncthreads();

    // ---- phase A: chunk-wv (mass, d2*mass) for all 64 pixels of row pi ----
    float mass = 0.f, d2m = 0.f;
    #pragma unroll 8
    for (int k = 0; k < 64; ++k) {
        uint32_t eo = (uint32_t)__builtin_amdgcn_readlane((int)ev.x, k);
        float d2 = __uint_as_float((uint32_t)__builtin_amdgcn_readlane((int)ev.y, k));
        int row = pi + (int)(eo >> 7) - 63;                       // uniform
        unsigned rbase = (((unsigned)row < 64u) ? (unsigned)row : 64u) << 6;  // scalar cselect
        int qj = lane + (int)(eo & 127u) - 63;
        float wq = w[rbase + ((unsigned)qj & 63u)];
        wq = ((unsigned)qj < 64u) ? wq : 0.f;
        mass += wq;
        d2m = fmaf(d2, wq, d2m);
    }
    summ[wv][lane] = make_float2(mass, d2m);
    __syncthreads();
    if (wv != 0) return;

    // ---- phase B (wave 0): per-lane pixel = column `lane` of row pi ----
    float bound = 0.f;
    #pragma unroll
    for (int i = 0; i < NCHUNK; ++i) bound += red[i];
    bound *= 0.05f;

    // scan chunks 0..14 (a chunk-15 crossing is handled by the walk itself)
    float rem = bound, cumd = 0.f;
    int cstar = NCHUNK - 1;
    bool found = false;
    #pragma unroll
    for (int c = 0; c < NCHUNK - 1; ++c) {
        float2 p = summ[c][lane];
        bool cross = (!found) && (p.x >= rem);
        cstar = cross ? c : cstar;
        bool adv = (!found) && (!cross);
        rem  = adv ? rem - p.x : rem;
        cumd = adv ? cumd + p.y : cumd;
        found = found || cross;
    }

    // walk the 64 entries of the per-lane crossing chunk (divergent data,
    // uniform trip count; independent global loads batch in the vm queue)
    float val = 0.f;
    bool done = false;
    int pos = cstar << 6;
    #pragma unroll 8
    for (int k = 0; k < 64; ++k) {
        uint2 e = gt[pos + k];
        int qi = pi + (int)((e.x >> 7) & 127u) - 63;
        int qj = lane + (int)(e.x & 127u) - 63;
        bool ok = ((unsigned)qi < 64u) && ((unsigned)qj < 64u) && !done;
        float wq = w[(((unsigned)qi & 63u) << 6) | ((unsigned)qj & 63u)];
        wq = ok ? wq : 0.f;
        float d2 = __uint_as_float(e.y);
        bool cross = (!done) && (wq >= rem);
        val  = cross ? fmaf(d2, rem, cumd) : val;
        done = done || cross;
        cumd = fmaf(d2, wq, cumd);
        rem -= wq;
    }
    pos += 64;

    // exact fallback (ulp-boundary chunk detection or crossing beyond the
    // speculative window); practically never iterates
    while (__any(!done)) {
        int idx = pos < NPAD ? pos : NPAD - 1;
        uint2 e = gt[idx];
        int qi = pi + (int)((e.x >> 7) & 127u) - 63;
        int qj = lane + (int)(e.x & 127u) - 63;
        bool ok = ((unsigned)qi < 64u) && ((unsigned)qj < 64u) && !done;
        float wq = w[(((unsigned)qi & 63u) << 6) | ((unsigned)qj & 63u)];
        wq = ok ? wq : 0.f;
        float d2 = __uint_as_float(e.y);
        bool cross = (!done) && ((wq >= rem) || (pos >= NPAD));
        val  = cross ? fmaf(d2, rem, cumd) : val;
        done = done || cross;
        cumd = fmaf(d2, wq, cumd);
        rem -= wq;
        pos++;
    }

    out[(size_t)bc * HW + (pi << 6) + lane] = sqrtf(val / bound);
}

extern "C" void kernel_launch(void* const* d_in, const int* in_sizes, int n_in,
                              void* d_out, int out_size, void* d_ws, size_t ws_size,
                              hipStream_t stream) {
    const float* x = (const float*)d_in[0];
    float* out = (float*)d_out;
    int BC = in_sizes[0] / HW;   // 12 for (4,3,64,64)
    dtm_kernel<<<BC * 64, 1024, 0, stream>>>(x, out);
}

// Round 7
// 62.321 us; speedup vs baseline: 1.2184x; 1.2184x over previous
//
#include <hip/hip_runtime.h>
#include <stdint.h>

// DTM layer: B=4, C=3, H=W=64. Unit lattice => dist^2 = di^2 + dj^2.
// Per pixel: walk lattice offsets in increasing d2, accumulate weight until
// crossing bound = 0.05*sum(w); val = cumd_before + d2*(bound - cum_before).
// KEY EXACTNESS FACTS: (1) within an equal-d2 shell the result is invariant
// to order AND to grouping granularity; (2) the reference's max_k clip never
// binds. So we walk GROUPS {(+-d, +-e)} (equal d2) instead of entries, and
// use wpair[d][j] = w[pi-d][j] + w[pi+d][j] (zero-haloed) so each group is
// 2 validity-free LDS gathers. Sorted group table is compile-time.
//
// Round-7 structure: 512-thread block (8 waves) per (b,c,row); 4 blocks/CU.
//  - build wpair (19 rows x 100 cols, 7.6 KB) straight from global x;
//    bound via direct global float4 reduce (no 16 KB w staging at all).
//  - Phase A: wave wv computes chunks 2wv, 2wv+1 (20 groups each) partial
//    (mass, d2*mass) per pixel; meta preloaded to VGPRs, readlane-broadcast
//    (scalar decode, pure-lgkm ds_read queue).
//  - Phase B (wave 0): scan 15 chunk summaries, walk the 20 groups of the
//    per-lane crossing chunk; exact global-x fallback past the window
//    (practically never taken; window covers >=1024 sorted entries).

#define HW     4096
#define NBIN   8192
#define WIN_D2 360
#define DMAX   18          // floor(sqrt(360)); 19^2=361 > 360
#define HSTR   100         // wpair row stride = 64 + 2*18
#define HOFF   18
#define WROWS  19          // d = 0..18
#define WPN    (WROWS * HSTR)   // 1900 floats
#define NCHUNK 16
#define NG     4096        // all (d,e) in [0,64)^2 groups

struct GM { uint32_t de; float d2; };  // de = d | e<<6 | code<<12; code:0->sc1,1->sc0.5,2->sc0

constexpr int cnt_win_groups() {
    int n = 0;
    for (int d = 0; d < 64; ++d)
        for (int e = 0; e < 64; ++e)
            if (d * d + e * e <= WIN_D2) ++n;
    return n;
}
constexpr int cnt_win_entries() {
    int n = 0;
    for (int d = -63; d < 64; ++d)
        for (int e = -63; e < 64; ++e)
            if (d * d + e * e <= WIN_D2) ++n;
    return n;
}
constexpr int NWIN  = cnt_win_groups();              // 316
constexpr int GPC   = (NWIN + NCHUNK - 1) / NCHUNK;  // 20 groups per chunk
constexpr int NWINP = GPC * NCHUNK;                  // 320 (padded)
static_assert(cnt_win_entries() >= 1024, "window must cover worst crossing");
static_assert(NWIN <= NWINP && NWINP - NWIN < GPC, "pad only in last chunk");

struct GTabs { GM g[NG]; GM w[NWINP]; };

constexpr GTabs make_tabs() {
    GTabs t{};
    int cnt[NBIN] = {};
    for (int d = 0; d < 64; ++d)
        for (int e = 0; e < 64; ++e) cnt[d * d + e * e]++;
    int run = 0;
    for (int b = 0; b < NBIN; ++b) { int c = cnt[b]; cnt[b] = run; run += c; }
    for (int d = 0; d < 64; ++d)
        for (int e = 0; e < 64; ++e) {
            int d2 = d * d + e * e;
            int pos = cnt[d2]++;
            unsigned code = (e == 0) ? 1u : 0u;  // e==0 gathers same addr twice -> 0.5
            t.g[pos].de = (uint32_t)d | ((uint32_t)e << 6) | (code << 12);
            t.g[pos].d2 = (float)d2;
        }
    for (int i = 0; i < NWIN; ++i) t.w[i] = t.g[i];
    for (int i = NWIN; i < NWINP; ++i) { t.w[i].de = (2u << 12); t.w[i].d2 = (float)WIN_D2; }
    return t;
}
__device__ const GTabs g_t = make_tabs();

__global__ __launch_bounds__(512, 8) void dtm_kernel(const float* __restrict__ x,
                                                     float* __restrict__ out) {
    __shared__ float  wpair[WPN];          // 7.6 KB
    __shared__ float2 summ[NCHUNK][64];    // 8 KB
    __shared__ float  red[8];

    int bc   = blockIdx.x >> 6;
    int pi   = blockIdx.x & 63;   // row (uniform)
    int tid  = threadIdx.x;       // 0..511
    int lane = tid & 63;          // pixel column
    int wv   = tid >> 6;          // wave 0..7

    const float* __restrict__ xs = x + (size_t)bc * HW;

    // ---- bound: direct global float4 reduce (2 per thread) ----
    const float4* xb = (const float4*)xs;
    float4 a0 = xb[tid];
    float4 a1 = xb[tid + 512];
    float s = ((a0.x + a0.y) + (a0.z + a0.w)) + ((a1.x + a1.y) + (a1.z + a1.w));
    #pragma unroll
    for (int off = 32; off >= 1; off >>= 1) s += __shfl_down(s, off, 64);
    if (lane == 0) red[wv] = s;

    // ---- build zero-haloed wpair[d][c]: w[pi-d][j] + w[pi+d][j] (d=0 single) ----
    for (int idx = tid; idx < WPN; idx += 512) {
        int d = idx / HSTR;
        int c = idx - d * HSTR;
        int j = c - HOFF;           // -18..81
        float v = 0.f;
        if ((unsigned)j < 64u) {
            int rm = pi - d, rp = pi + d;
            if (rm >= 0) v += xs[rm * 64 + j];
            if (d > 0 && rp < 64) v += xs[rp * 64 + j];
        }
        wpair[idx] = v;
    }

    // meta for this wave's two chunks, one group per lane (reg-resident)
    const GM* __restrict__ mw = g_t.w;
    int li = lane < GPC ? lane : GPC - 1;
    GM mv0 = mw[(2 * wv)     * GPC + li];
    GM mv1 = mw[(2 * wv + 1) * GPC + li];
    __syncthreads();

    // ---- phase A: two chunk partials (mass, d2*mass) per pixel ----
    #pragma unroll
    for (int h = 0; h < 2; ++h) {
        GM mv = h ? mv1 : mv0;
        float m0 = 0.f, dm0 = 0.f;
        #pragma unroll 5
        for (int k = 0; k < GPC; ++k) {
            uint32_t de = (uint32_t)__builtin_amdgcn_readlane((int)mv.de, k);
            float d2 = __uint_as_float((uint32_t)__builtin_amdgcn_readlane(__float_as_int(mv.d2), k));
            int d = de & 63, e = (de >> 6) & 63;
            unsigned code = de >> 12;
            float sc = code == 0 ? 1.f : (code == 1 ? 0.5f : 0.f);  // scalar cselects
            int base = d * HSTR + HOFF;                              // scalar
            float g1 = wpair[base + lane - e];
            float g2 = wpair[base + lane + e];
            float m = sc * (g1 + g2);
            m0 += m;
            dm0 = fmaf(d2, m, dm0);
        }
        summ[2 * wv + h][lane] = make_float2(m0, dm0);
    }
    __syncthreads();
    if (wv != 0) return;

    // ---- phase B (wave 0): per-lane pixel = column lane of row pi ----
    float bound = 0.f;
    #pragma unroll
    for (int i = 0; i < 8; ++i) bound += red[i];
    bound *= 0.05f;

    float rem = bound, cumd = 0.f;
    int cstar = NCHUNK - 1;
    bool found = false;
    #pragma unroll
    for (int c = 0; c < NCHUNK - 1; ++c) {
        float2 p = summ[c][lane];
        bool cross = (!found) && (p.x >= rem);
        cstar = cross ? c : cstar;
        bool adv = (!found) && (!cross);
        rem   = adv ? rem - p.x : rem;
        cumd  = adv ? cumd + p.y : cumd;
        found = found || cross;
    }

    // walk the 20 groups of the crossing chunk (divergent meta, L2-hot)
    float val = 0.f;
    bool done = false;
    int g0 = cstar * GPC;
    #pragma unroll 4
    for (int k = 0; k < GPC; ++k) {
        GM mm = mw[g0 + k];
        int d = mm.de & 63, e = (mm.de >> 6) & 63;
        unsigned code = mm.de >> 12;
        float sc = code == 0 ? 1.f : (code == 1 ? 0.5f : 0.f);
        int base = d * HSTR + HOFF + lane;
        float m = sc * (wpair[base - e] + wpair[base + e]);
        float wq = done ? 0.f : m;
        bool cross = (!done) && (wq >= rem);
        val  = cross ? fmaf(mm.d2, rem, cumd) : val;
        done = done || cross;
        cumd = fmaf(mm.d2, wq, cumd);
        rem -= wq;
    }

    // exact fallback beyond the window / ulp chunk-boundary cases.
    // 4-term global-x gather; sc deduplicates (d==0 / e==0 double counts).
    int pos = g0 + GPC; if (pos > NWIN) pos = NWIN;
    const GM* __restrict__ mg = g_t.g;
    while (__any(!done)) {
        int ix = pos < NG ? pos : NG - 1;
        GM mm = mg[ix];
        int d = mm.de & 63, e = (mm.de >> 6) & 63;
        float sc = ((mm.de >> 12) == 1u) ? 0.5f : 1.f;
        if (d == 0) sc *= 0.5f;
        int rm = pi - d, rp = pi + d;
        int cm = lane - e, cp = lane + e;
        float m = 0.f;
        if (rm >= 0 && cm >= 0) m += xs[rm * 64 + cm];
        if (rm >= 0 && cp < 64) m += xs[rm * 64 + cp];
        if (rp < 64 && cm >= 0) m += xs[rp * 64 + cm];
        if (rp < 64 && cp < 64) m += xs[rp * 64 + cp];
        m *= sc;
        float wq = done ? 0.f : m;
        bool cross = (!done) && ((wq >= rem) || (pos >= NG));
        val  = cross ? fmaf(mm.d2, rem, cumd) : val;
        done = done || cross;
        cumd = fmaf(mm.d2, wq, cumd);
        rem -= wq;
        pos++;
    }

    out[(size_t)bc * HW + (pi << 6) + lane] = sqrtf(val / bound);
}

extern "C" void kernel_launch(void* const* d_in, const int* in_sizes, int n_in,
                              void* d_out, int out_size, void* d_ws, size_t ws_size,
                              hipStream_t stream) {
    const float* x = (const float*)d_in[0];
    float* out = (float*)d_out;
    int BC = in_sizes[0] / HW;   // 12 for (4,3,64,64)
    dtm_kernel<<<BC * 64, 512, 0, stream>>>(x, out);
}

// Round 8
// 62.013 us; speedup vs baseline: 1.2244x; 1.0050x over previous
//
#include <hip/hip_runtime.h>
#include <stdint.h>

// DTM layer: B=4, C=3, H=W=64. Unit lattice => dist^2 = di^2 + dj^2.
// Per pixel: walk lattice offsets in increasing d2, accumulate weight until
// crossing bound = 0.05*sum(w); val = cumd_before + d2*(bound - cum_before).
// EXACTNESS: (1) equal-d2 shells are order- and grouping-invariant, so we
// walk symmetry GROUPS {(+-d,+-e)} via wpair[d][j] = w[pi-d][j] + w[pi+d][j]
// (zero-haloed; 2 validity-free LDS gathers per group); (2) the reference's
// max_k clip never binds; (3) any crossing beyond the speculative window is
// resolved by an exact global-memory fallback walk.
//
// Round-8: ADAPTIVE WINDOW. Crossing needs ~205 effective entries
// (n* = 0.05*4096, sigma ~8.5). Per-group entry yield depends on row
// geometry (interior rows: worst lane still gets 2 reflections/group; edge
// rows' corner lanes get 1). Compile-time per-row tables nc[pi] (chunks to
// compute, NEED=260 ~ n*+6.5sigma at worst-lane yield) and dmax[pi] (wpair
// rows to build) cut phase-A work ~2x on average vs the fixed 16-chunk
// window. Chunk->wave map wv+8h: interior rows (nc<=8) do one chunk/wave.
// Structure: 512-thr block (8 waves) per (b,c,row); branchless wpair build;
// meta readlane-broadcast (pure-lgkm ds_read queue); phase B scans nc chunk
// summaries and walks the 20 groups of the per-lane crossing chunk.

#define HW     4096
#define NBIN   8192
#define WIN_D2 360
#define HSTR   100         // wpair row stride = 64 + 2*18
#define HOFF   18
#define WROWS  19          // d = 0..18
#define WPN    (WROWS * HSTR)
#define NCHUNK 16
#define NG     4096        // all (d,e) in [0,64)^2 groups
#define NEED   260         // worst-lane effective entries to cover crossing

struct GM { uint32_t de; float d2; };  // de = d | e<<6 | code<<12; code:0->sc1,1->sc0.5,2->sc0

constexpr int cnt_win_groups() {
    int n = 0;
    for (int d = 0; d < 64; ++d)
        for (int e = 0; e < 64; ++e)
            if (d * d + e * e <= WIN_D2) ++n;
    return n;
}
constexpr int NWIN  = cnt_win_groups();              // 316
constexpr int GPC   = 20;
constexpr int NWINP = GPC * NCHUNK;                  // 320

struct GTabs { GM g[NG]; GM w[NWINP]; int nc[64]; int dmax[64]; };

constexpr GTabs make_tabs() {
    GTabs t{};
    int cnt[NBIN] = {};
    for (int d = 0; d < 64; ++d)
        for (int e = 0; e < 64; ++e) cnt[d * d + e * e]++;
    int run = 0;
    for (int b = 0; b < NBIN; ++b) { int c = cnt[b]; cnt[b] = run; run += c; }
    for (int d = 0; d < 64; ++d)
        for (int e = 0; e < 64; ++e) {
            int d2 = d * d + e * e;
            int pos = cnt[d2]++;
            unsigned code = (e == 0) ? 1u : 0u;  // e==0: same addr twice -> 0.5
            t.g[pos].de = (uint32_t)d | ((uint32_t)e << 6) | (code << 12);
            t.g[pos].d2 = (float)d2;
        }
    for (int i = 0; i < NWIN; ++i) t.w[i] = t.g[i];
    for (int i = NWIN; i < NWINP; ++i) { t.w[i].de = (2u << 12); t.w[i].d2 = (float)WIN_D2; }
    // per-row chunk count: simulate worst lane (col 0) cumulative entry yield
    for (int pi = 0; pi < 64; ++pi) {
        int md = pi < 63 - pi ? pi : 63 - pi;   // row margin
        int y = 0, G = 0;
        while (y < NEED && G < NWIN) {
            int d = (int)(t.g[G].de & 63u);
            y += (d == 0) ? 1 : ((d <= md) ? 2 : 1);
            ++G;
        }
        int nc = (G + GPC - 1) / GPC;
        if (nc < 1) nc = 1;
        t.nc[pi] = nc;
        int dm = 0;
        for (int i = 0; i < nc * GPC && i < NWIN; ++i) {
            int d = (int)(t.g[i].de & 63u);
            if (d > dm) dm = d;
        }
        t.dmax[pi] = dm;
    }
    return t;
}
__device__ const GTabs g_t = make_tabs();

constexpr int max_nc() {
    GTabs t = make_tabs();
    int m = 0;
    for (int i = 0; i < 64; ++i) if (t.nc[i] > m) m = t.nc[i];
    return m;
}
static_assert(max_nc() * GPC <= NWIN, "window table must cover worst row");

__global__ __launch_bounds__(512, 8) void dtm_kernel(const float* __restrict__ x,
                                                     float* __restrict__ out) {
    __shared__ float  wpair[WPN];          // 7.6 KB
    __shared__ float2 summ[NCHUNK][64];    // 8 KB
    __shared__ float  red[8];

    int bc   = blockIdx.x >> 6;
    int pi   = blockIdx.x & 63;   // row (uniform)
    int tid  = threadIdx.x;       // 0..511
    int lane = tid & 63;          // pixel column
    int wv   = tid >> 6;          // wave 0..7

    const float* __restrict__ xs = x + (size_t)bc * HW;
    int nc  = __builtin_amdgcn_readfirstlane(g_t.nc[pi]);
    int dmx = __builtin_amdgcn_readfirstlane(g_t.dmax[pi]);

    // ---- bound: direct global float4 reduce (2 per thread) ----
    const float4* xb = (const float4*)xs;
    float4 a0 = xb[tid];
    float4 a1 = xb[tid + 512];
    float s = ((a0.x + a0.y) + (a0.z + a0.w)) + ((a1.x + a1.y) + (a1.z + a1.w));
    #pragma unroll
    for (int off = 32; off >= 1; off >>= 1) s += __shfl_down(s, off, 64);
    if (lane == 0) red[wv] = s;

    // ---- build zero-haloed wpair rows 0..dmx, branchless (loads batch) ----
    int wlen = (dmx + 1) * HSTR;
    for (int idx = tid; idx < wlen; idx += 512) {
        int d = idx / HSTR;
        int c = idx - d * HSTR;
        int j = c - HOFF;                    // -18..81
        bool jv = (unsigned)j < 64u;
        int ja = jv ? j : 0;
        int rm = pi - d, rp = pi + d;
        float vm = xs[(rm > 0 ? rm : 0) * 64 + ja];
        float vp = xs[(rp < 63 ? rp : 63) * 64 + ja];
        float v = (rm >= 0 ? vm : 0.f) + ((d > 0 && rp < 64) ? vp : 0.f);
        wpair[idx] = jv ? v : 0.f;
    }

    // meta for this wave's (up to) two chunks, reg-resident
    const GM* __restrict__ mw = g_t.w;
    int li = lane < GPC ? lane : GPC - 1;
    GM mv0 = mw[wv * GPC + li];
    GM mv1 = mw[(wv + 8) * GPC + li];
    __syncthreads();

    // ---- phase A: chunk partials (mass, d2*mass) per pixel ----
    #pragma unroll
    for (int h = 0; h < 2; ++h) {
        int chunk = wv + 8 * h;
        if (chunk < nc) {                    // wave-uniform, per-chunk branch
            GM mv = h ? mv1 : mv0;
            float m0 = 0.f, dm0 = 0.f;
            #pragma unroll 5
            for (int k = 0; k < GPC; ++k) {
                uint32_t de = (uint32_t)__builtin_amdgcn_readlane((int)mv.de, k);
                float d2 = __uint_as_float(
                    (uint32_t)__builtin_amdgcn_readlane(__float_as_int(mv.d2), k));
                int d = de & 63, e = (de >> 6) & 63;
                unsigned code = de >> 12;
                float sc = code == 0 ? 1.f : (code == 1 ? 0.5f : 0.f);
                int base = d * HSTR + HOFF;                  // scalar
                float g1 = wpair[base + lane - e];
                float g2 = wpair[base + lane + e];
                float m = sc * (g1 + g2);
                m0 += m;
                dm0 = fmaf(d2, m, dm0);
            }
            summ[chunk][lane] = make_float2(m0, dm0);
        }
    }
    __syncthreads();
    if (wv != 0) return;

    // ---- phase B (wave 0): per-lane pixel = column lane of row pi ----
    float bound = 0.f;
    #pragma unroll
    for (int i = 0; i < 8; ++i) bound += red[i];
    bound *= 0.05f;

    float rem = bound, cumd = 0.f;
    int cstar = nc - 1;
    bool found = false;
    #pragma unroll
    for (int c = 0; c < NCHUNK - 1; ++c) {
        if (c < nc - 1) {                    // uniform predicate
            float2 p = summ[c][lane];
            bool cross = (!found) && (p.x >= rem);
            cstar = cross ? c : cstar;
            bool adv = (!found) && (!cross);
            rem   = adv ? rem - p.x : rem;
            cumd  = adv ? cumd + p.y : cumd;
            found = found || cross;
        }
    }

    // walk the 20 groups of the crossing chunk
    float val = 0.f;
    bool done = false;
    int g0 = cstar * GPC;
    #pragma unroll 4
    for (int k = 0; k < GPC; ++k) {
        GM mm = mw[g0 + k];
        int d = mm.de & 63, e = (mm.de >> 6) & 63;
        unsigned code = mm.de >> 12;
        float sc = code == 0 ? 1.f : (code == 1 ? 0.5f : 0.f);
        int base = d * HSTR + HOFF + lane;
        float m = sc * (wpair[base - e] + wpair[base + e]);
        float wq = done ? 0.f : m;
        bool cross = (!done) && (wq >= rem);
        val  = cross ? fmaf(mm.d2, rem, cumd) : val;
        done = done || cross;
        cumd = fmaf(mm.d2, wq, cumd);
        rem -= wq;
    }

    // exact fallback beyond the walked chunk (ulp boundary cases or crossing
    // past the adaptive window); practically never iterates
    int pos = g0 + GPC; if (pos > NWIN) pos = NWIN;
    const GM* __restrict__ mg = g_t.g;
    while (__any(!done)) {
        int ix = pos < NG ? pos : NG - 1;
        GM mm = mg[ix];
        int d = mm.de & 63, e = (mm.de >> 6) & 63;
        float sc = ((mm.de >> 12) == 1u) ? 0.5f : 1.f;
        if (d == 0) sc *= 0.5f;
        int rm = pi - d, rp = pi + d;
        int cm = lane - e, cp = lane + e;
        float m = 0.f;
        if (rm >= 0 && cm >= 0) m += xs[rm * 64 + cm];
        if (rm >= 0 && cp < 64) m += xs[rm * 64 + cp];
        if (rp < 64 && cm >= 0) m += xs[rp * 64 + cm];
        if (rp < 64 && cp < 64) m += xs[rp * 64 + cp];
        m *= sc;
        float wq = done ? 0.f : m;
        bool cross = (!done) && ((wq >= rem) || (pos >= NG));
        val  = cross ? fmaf(mm.d2, rem, cumd) : val;
        done = done || cross;
        cumd = fmaf(mm.d2, wq, cumd);
        rem -= wq;
        pos++;
    }

    out[(size_t)bc * HW + (pi << 6) + lane] = sqrtf(val / bound);
}

extern "C" void kernel_launch(void* const* d_in, const int* in_sizes, int n_in,
                              void* d_out, int out_size, void* d_ws, size_t ws_size,
                              hipStream_t stream) {
    const float* x = (const float*)d_in[0];
    float* out = (float*)d_out;
    int BC = in_sizes[0] / HW;   // 12 for (4,3,64,64)
    dtm_kernel<<<BC * 64, 512, 0, stream>>>(x, out);
}